// Round 5
// baseline (128.059 us; speedup 1.0000x reference)
//
#include <hip/hip_runtime.h>

#define NN 10000
#define KK 64
#define CC 128
#define OUTOFF (NN * CC)
#define NA 256        // split-K blocks in kA
#define CHUNKS_A 625  // 625 * 16 == 10000

__device__ __forceinline__ float4 f4fma(float s, float4 v, float4 a) {
    a.x = fmaf(s, v.x, a.x); a.y = fmaf(s, v.y, a.y);
    a.z = fmaf(s, v.z, a.z); a.w = fmaf(s, v.w, a.w);
    return a;
}
__device__ __forceinline__ float4 f4add(float4 a, float4 b) {
    a.x += b.x; a.y += b.y; a.z += b.z; a.w += b.w; return a;
}

// ws layout (floats): [0 .. NA*16384)  partials [b][m][k][c]   (16.8 MB)
//                     [NA*16384 .. +16384)  UVW [m][k][c]      (64 KB)

// ---------------- kA: partial U,V = split-K of Q^T X ----------------
// 256 threads, register tile 4k x 8c: 6 ds_read_b128 per row serve 128 FMA.
__global__ __launch_bounds__(256) void kA(const float* __restrict__ re,
                                          const float* __restrict__ im,
                                          const float* __restrict__ Qr,
                                          const float* __restrict__ Qi,
                                          float* __restrict__ part)
{
    __shared__ float4 smem[1536];   // Qr 256 | Qi 256 | re 512 | im 512  (24 KB)
    const int t = threadIdx.x;
    const int bid = blockIdx.x;
    const int kt = t & 15;          // k0 = 4*kt
    const int ct = t >> 4;          // c0 = 8*ct (0..15)
    const int row_q = t >> 4, q_q = t & 15;   // staging: Q row 0..15
    const int row_x = t >> 5, q_x = t & 31;   // staging: X row 0..7 (+8 for 2nd)

    const float4* gqr = (const float4*)Qr;
    const float4* gqi = (const float4*)Qi;
    const float4* gre = (const float4*)re;
    const float4* gim = (const float4*)im;

    float aU[4][8] = {}, aV[4][8] = {};

    int cb = bid;
    {
        const int n0 = cb * 16;
        // initial prefetch happens inline below via r0..r5 pattern
    }
    float4 r0 = gqr[(size_t)(cb * 16 + row_q) * 16 + q_q];
    float4 r1 = gqi[(size_t)(cb * 16 + row_q) * 16 + q_q];
    float4 r2 = gre[(size_t)(cb * 16 + row_x) * 32 + q_x];
    float4 r3 = gre[(size_t)(cb * 16 + 8 + row_x) * 32 + q_x];
    float4 r4 = gim[(size_t)(cb * 16 + row_x) * 32 + q_x];
    float4 r5 = gim[(size_t)(cb * 16 + 8 + row_x) * 32 + q_x];

    while (true) {
        smem[t] = r0; smem[256 + t] = r1;
        smem[512 + t] = r2; smem[768 + t] = r3;
        smem[1024 + t] = r4; smem[1280 + t] = r5;
        __syncthreads();
        const int nx = cb + NA;
        if (nx < CHUNKS_A) {   // prefetch next chunk into registers during compute
            const int m0 = nx * 16;
            r0 = gqr[(size_t)(m0 + row_q) * 16 + q_q];
            r1 = gqi[(size_t)(m0 + row_q) * 16 + q_q];
            r2 = gre[(size_t)(m0 + row_x) * 32 + q_x];
            r3 = gre[(size_t)(m0 + 8 + row_x) * 32 + q_x];
            r4 = gim[(size_t)(m0 + row_x) * 32 + q_x];
            r5 = gim[(size_t)(m0 + 8 + row_x) * 32 + q_x];
        }
#pragma unroll 4
        for (int rr = 0; rr < 16; ++rr) {
            float4 q_r = smem[rr * 16 + kt];
            float4 q_i = smem[256 + rr * 16 + kt];
            float4 xr0 = smem[512 + rr * 32 + 2 * ct];
            float4 xr1 = smem[512 + rr * 32 + 2 * ct + 1];
            float4 xi0 = smem[1024 + rr * 32 + 2 * ct];
            float4 xi1 = smem[1024 + rr * 32 + 2 * ct + 1];
            float qr_[4] = {q_r.x, q_r.y, q_r.z, q_r.w};
            float qi_[4] = {q_i.x, q_i.y, q_i.z, q_i.w};
            float xr_[8] = {xr0.x, xr0.y, xr0.z, xr0.w, xr1.x, xr1.y, xr1.z, xr1.w};
            float xi_[8] = {xi0.x, xi0.y, xi0.z, xi0.w, xi1.x, xi1.y, xi1.z, xi1.w};
#pragma unroll
            for (int a = 0; a < 4; ++a)
#pragma unroll
                for (int b = 0; b < 8; ++b) {
                    aU[a][b] = fmaf(qr_[a], xr_[b], aU[a][b]);
                    aU[a][b] = fmaf(qi_[a], xi_[b], aU[a][b]);
                    aV[a][b] = fmaf(qi_[a], xr_[b], aV[a][b]);
                    aV[a][b] = fmaf(-qr_[a], xi_[b], aV[a][b]);
                }
        }
        __syncthreads();
        if (nx >= CHUNKS_A) break;
        cb = nx;
    }
    float* base = part + (size_t)bid * 16384;
    const int k0 = kt * 4, c0 = ct * 8;
#pragma unroll
    for (int a = 0; a < 4; ++a) {
        *(float4*)(base + (k0 + a) * CC + c0)     = make_float4(aU[a][0], aU[a][1], aU[a][2], aU[a][3]);
        *(float4*)(base + (k0 + a) * CC + c0 + 4) = make_float4(aU[a][4], aU[a][5], aU[a][6], aU[a][7]);
        *(float4*)(base + 8192 + (k0 + a) * CC + c0)     = make_float4(aV[a][0], aV[a][1], aV[a][2], aV[a][3]);
        *(float4*)(base + 8192 + (k0 + a) * CC + c0 + 4) = make_float4(aV[a][4], aV[a][5], aV[a][6], aV[a][7]);
    }
}

// ---------------- kRB: reduce 256 partials -> row, then UVW = TT * row @ W ----------------
// grid 128 = (m in {U,V}) x (k in 0..63); 256 threads; float4 loads, 4 chains
__global__ __launch_bounds__(256) void kRB(const float* __restrict__ part,
                                           const float* __restrict__ Ritz,
                                           const int* __restrict__ ldp,
                                           const float* __restrict__ W,
                                           float* __restrict__ UVW)
{
    __shared__ float4 red4[256];
    __shared__ float rowS[128];
    const int t = threadIdx.x;
    const int m = blockIdx.x >> 6, k = blockIdx.x & 63;
    const int q = t & 31, sl = t >> 5;   // q: float4 col group, sl: slice lane (0..7)

    const float4* p = (const float4*)part + (size_t)sl * 4096 + m * 2048 + k * 32 + q;
    float4 z = make_float4(0.f, 0.f, 0.f, 0.f);
    float4 s0 = z, s1 = z, s2 = z, s3 = z;
#pragma unroll 2
    for (int jj = 0; jj < 8; ++jj) {
        s0 = f4add(s0, p[0]);
        s1 = f4add(s1, p[(size_t)8  * 4096]);
        s2 = f4add(s2, p[(size_t)16 * 4096]);
        s3 = f4add(s3, p[(size_t)24 * 4096]);
        p += (size_t)32 * 4096;
    }
    red4[t] = f4add(f4add(s0, s1), f4add(s2, s3));
    __syncthreads();
    if (t < 32) {
        float4 tot = z;
#pragma unroll
        for (int g = 0; g < 8; ++g) tot = f4add(tot, red4[g * 32 + t]);
        ((float4*)rowS)[t] = tot;
    }
    __syncthreads();
    if (t < 128) {
        float acc = 0.f;
#pragma unroll 8
        for (int cp = 0; cp < 128; ++cp)
            acc = fmaf(rowS[cp], W[cp * 128 + t], acc);
        const int ld = *ldp;
        const float rz = Ritz[k];
        float tt = 1.f;
        for (int i = 0; i < ld; ++i) tt *= rz;
        UVW[m * 8192 + k * 128 + t] = tt * acc;
    }
}

// ---------------- kC: res = Q @ UVW + masked-ReLU epilogue ----------------
// 625 blocks x 128 threads, 16 rows/block (exact). Thread = 4 rows x 4 cols:
// 2 ds_read_b128 per k serve 64 FMA.
__global__ __launch_bounds__(128) void kC(const float* __restrict__ re,
                                          const float* __restrict__ im,
                                          const float* __restrict__ Qr,
                                          const float* __restrict__ Qi,
                                          const float* __restrict__ UVW,
                                          float* __restrict__ out)
{
    __shared__ float4 s[4096];   // [0..2047] UW [k][c4], [2048..4095] VW [k][c4]
    const int t = threadIdx.x;
    {
        const float4* g = (const float4*)UVW;
        for (int i = t; i < 4096; i += 128) s[i] = g[i];
    }
    __syncthreads();
    const int ct = t & 31;   // float4 col group: cols 4*ct..+3
    const int r  = t >> 5;   // 0..3; rows r, r+4, r+8, r+12 of this 16-row chunk
    const int n0 = blockIdx.x * 16 + r;

    const float4* qr0 = (const float4*)(Qr + (size_t)n0 * KK);
    const float4* qi0 = (const float4*)(Qi + (size_t)n0 * KK);
    const float4* qr1 = (const float4*)(Qr + (size_t)(n0 + 4) * KK);
    const float4* qi1 = (const float4*)(Qi + (size_t)(n0 + 4) * KK);
    const float4* qr2 = (const float4*)(Qr + (size_t)(n0 + 8) * KK);
    const float4* qi2 = (const float4*)(Qi + (size_t)(n0 + 8) * KK);
    const float4* qr3 = (const float4*)(Qr + (size_t)(n0 + 12) * KK);
    const float4* qi3 = (const float4*)(Qi + (size_t)(n0 + 12) * KK);

    float4 z = make_float4(0.f, 0.f, 0.f, 0.f);
    float4 R[4] = {z, z, z, z}, I[4] = {z, z, z, z};

#pragma unroll 4
    for (int k4 = 0; k4 < 16; ++k4) {
        float4 QR[4] = {qr0[k4], qr1[k4], qr2[k4], qr3[k4]};
        float4 QI[4] = {qi0[k4], qi1[k4], qi2[k4], qi3[k4]};
        float ar[4][4], ai[4][4];
#pragma unroll
        for (int w = 0; w < 4; ++w) {
            ar[w][0] = QR[w].x; ar[w][1] = QR[w].y; ar[w][2] = QR[w].z; ar[w][3] = QR[w].w;
            ai[w][0] = QI[w].x; ai[w][1] = QI[w].y; ai[w][2] = QI[w].z; ai[w][3] = QI[w].w;
        }
#pragma unroll
        for (int j = 0; j < 4; ++j) {
            const int k = k4 * 4 + j;
            float4 uw = s[k * 32 + ct];
            float4 vw = s[2048 + k * 32 + ct];
#pragma unroll
            for (int w = 0; w < 4; ++w) {
                R[w] = f4fma(ar[w][j], uw, R[w]); R[w] = f4fma(ai[w][j], vw, R[w]);
                I[w] = f4fma(ai[w][j], uw, I[w]); I[w] = f4fma(-ar[w][j], vw, I[w]);
            }
        }
    }
    const int cc = ct * 4;
#pragma unroll
    for (int w = 0; w < 4; ++w) {
        const int na = n0 + w * 4;
        float4 rin = *(const float4*)(re + (size_t)na * CC + cc);
        float4 iin = *(const float4*)(im + (size_t)na * CC + cc);
        float4 orr, oii;
        orr.x = rin.x + (R[w].x >= 0.f ? R[w].x : 0.f); oii.x = iin.x + (R[w].x >= 0.f ? I[w].x : 0.f);
        orr.y = rin.y + (R[w].y >= 0.f ? R[w].y : 0.f); oii.y = iin.y + (R[w].y >= 0.f ? I[w].y : 0.f);
        orr.z = rin.z + (R[w].z >= 0.f ? R[w].z : 0.f); oii.z = iin.z + (R[w].z >= 0.f ? I[w].z : 0.f);
        orr.w = rin.w + (R[w].w >= 0.f ? R[w].w : 0.f); oii.w = iin.w + (R[w].w >= 0.f ? I[w].w : 0.f);
        *(float4*)(out + (size_t)na * CC + cc)          = orr;
        *(float4*)(out + OUTOFF + (size_t)na * CC + cc) = oii;
    }
}

extern "C" void kernel_launch(void* const* d_in, const int* in_sizes, int n_in,
                              void* d_out, int out_size, void* d_ws, size_t ws_size,
                              hipStream_t stream) {
    const float* re   = (const float*)d_in[0];
    const float* im   = (const float*)d_in[1];
    const float* Qr   = (const float*)d_in[2];
    const float* Qi   = (const float*)d_in[3];
    const float* Ritz = (const float*)d_in[4];
    const float* W    = (const float*)d_in[5];
    const int*   ldp  = (const int*)d_in[6];
    float* out = (float*)d_out;
    float* ws  = (float*)d_ws;

    float* part = ws;                          // NA * 16384 floats
    float* UVW  = ws + (size_t)NA * 16384;     // 16384 floats

    kA <<<NA,  256, 0, stream>>>(re, im, Qr, Qi, part);
    kRB<<<128, 256, 0, stream>>>(part, Ritz, ldp, W, UVW);
    kC <<<625, 128, 0, stream>>>(re, im, Qr, Qi, UVW, out);
}